// Round 7
// baseline (1119.167 us; speedup 1.0000x reference)
//
#include <hip/hip_runtime.h>
#include <cstdint>
#include <cstddef>

typedef __bf16 bf16;
typedef __bf16 bf16x4 __attribute__((ext_vector_type(4)));
typedef __bf16 bf16x8 __attribute__((ext_vector_type(8)));
typedef float  f32x4  __attribute__((ext_vector_type(4)));
typedef long long i64v;

#define NROWS   32768   // 4096 * 8  (X2 rows)
#define DBLK    512
#define H1N     1024
#define H2N     512
#define NEXP    6
#define NBATCH  4096
#define HALL    (NEXP * H1N)   // 6144 h1 cols across all experts
#define W2SCALE 32.0f
#define W2INV   0.03125f
#define SPLIT   8              // row chunks; h1 chunk = 25 MB -> L2/L3 resident

// async global->LDS, 16B per lane; LDS dest = wave-uniform base + lane*16
__device__ __forceinline__ void gld16(const void* g, void* l) {
    __builtin_amdgcn_global_load_lds(
        (const __attribute__((address_space(1))) void*)g,
        (__attribute__((address_space(3))) void*)l, 16, 0, 0);
}

// inf-safe fast tanh: 1 - 2/(exp(2x)+1)
__device__ __forceinline__ float fast_tanh(float x) {
    float e = __expf(2.0f * x);
    return 1.0f - __fdividef(2.0f, e + 1.0f);
}

__device__ __forceinline__ float hsum16(float v) {
    v += __shfl_xor(v, 1);
    v += __shfl_xor(v, 2);
    v += __shfl_xor(v, 4);
    v += __shfl_xor(v, 8);
    return v;
}

// bf16 tiles: swizzled LDS element offset (16B granule g of row r at g^(r&7))
__device__ __forceinline__ int swz(int row, int g) {
    return row * 64 + ((g ^ (row & 7)) * 8);
}
// fp8 tiles: 64B rows, 4 granules; granule g of row r lives at g^((r>>1)&3)
__device__ __forceinline__ int swz8(int row, int g) {
    return row * 64 + ((g ^ ((row >> 1) & 3)) << 4);
}

// ---------------- prep kernels ----------------

__global__ void cvt_bf16_kernel(const float* __restrict__ in,
                                bf16* __restrict__ out, int n4) {
    int i = blockIdx.x * blockDim.x + threadIdx.x;
    if (i >= n4) return;
    float4 v = ((const float4*)in)[i];
    bf16x4 o;
    o.x = (bf16)v.x; o.y = (bf16)v.y; o.z = (bf16)v.z; o.w = (bf16)v.w;
    ((bf16x4*)out)[i] = o;
}

// in: [E][K][N] f32 -> out: [E][N][K] bf16 (LDS-tiled transpose)
__global__ __launch_bounds__(256) void transpose_cvt(
    const float* __restrict__ in, bf16* __restrict__ out, int K, int N) {
    __shared__ bf16 tile[64][66];
    int e  = blockIdx.z;
    int n0 = blockIdx.x * 64;
    int k0 = blockIdx.y * 64;
    int c  = threadIdx.x & 63;
    int rb = threadIdx.x >> 6;   // 0..3
    const float* src = in + (size_t)e * K * N;
    bf16* dst = out + (size_t)e * N * K;
#pragma unroll
    for (int it = 0; it < 16; ++it) {
        int k = k0 + rb + it * 4;
        int n = n0 + c;
        if (k < K && n < N) tile[rb + it * 4][c] = (bf16)src[(size_t)k * N + n];
    }
    __syncthreads();
#pragma unroll
    for (int it = 0; it < 16; ++it) {
        int n = n0 + rb + it * 4;
        int k = k0 + c;
        if (n < N && k < K) dst[(size_t)n * K + k] = tile[c][rb + it * 4];
    }
}

// in: [E][K][N] f32 -> out: [E][N][K] fp8 e4m3, scaled
__global__ __launch_bounds__(256) void transpose_cvt_fp8(
    const float* __restrict__ in, uint8_t* __restrict__ out, int K, int N,
    float scale) {
    __shared__ float tile[64][65];
    int e  = blockIdx.z;
    int n0 = blockIdx.x * 64;
    int k0 = blockIdx.y * 64;
    int c  = threadIdx.x & 63;
    int rb = threadIdx.x >> 6;   // 0..3
    const float* src = in + (size_t)e * K * N;
    uint8_t* dst = out + (size_t)e * N * K;
#pragma unroll
    for (int it = 0; it < 16; ++it) {
        int k = k0 + rb + it * 4;
        int n = n0 + c;
        if (k < K && n < N) tile[rb + it * 4][c] = src[(size_t)k * N + n];
    }
    __syncthreads();
#pragma unroll
    for (int it = 0; it < 16; ++it) {
        int n = n0 + rb + it * 4;
        int k = k0 + c;
        if (n < N && k < K) {
            float v = tile[c][rb + it * 4] * scale;
            int p = __builtin_amdgcn_cvt_pk_fp8_f32(v, v, 0, false);
            dst[(size_t)n * K + k] = (uint8_t)(p & 0xff);
        }
    }
}

__global__ void zero_f32_kernel(float* __restrict__ p, int n) {
    int i = blockIdx.x * blockDim.x + threadIdx.x;
    if (i < n) p[i] = 0.0f;
}

// ---------------- router ----------------

__global__ __launch_bounds__(256, 2) void router_kernel(
    const bf16* __restrict__ xbf,   // [4096][4096]
    const bf16* __restrict__ Wr1t,  // [8][32][512]
    const float* __restrict__ br1,  // [8][32]
    const float* __restrict__ Wr2,  // [8][32][6]
    const float* __restrict__ br2,  // [8][6]
    float* __restrict__ routing) {  // [32768][6]
    __shared__ __align__(16) bf16 sA[128 * 64];
    __shared__ __align__(16) bf16 sB[32 * 64];
    const int tid = threadIdx.x;
    const int w = tid >> 6, l = tid & 63;
    const int s  = blockIdx.y;
    const int b0 = blockIdx.x * 128;
    const int wm = w * 32;
    const int srow = l >> 3, schk = (l & 7) * 8;
    const int fr = l & 15, fq = l >> 4;
    const bf16* Ab = xbf + (size_t)s * 512;
    const bf16* Bb = Wr1t + (size_t)s * (32 * 512);

    f32x4 acc[2][2];
#pragma unroll
    for (int i = 0; i < 2; ++i)
#pragma unroll
        for (int j = 0; j < 2; ++j) acc[i][j] = (f32x4){0.f, 0.f, 0.f, 0.f};

    for (int k0 = 0; k0 < 512; k0 += 64) {
        __syncthreads();
#pragma unroll
        for (int jj = 0; jj < 4; ++jj) {
            int row = w * 32 + jj * 8;
            gld16(Ab + (size_t)(b0 + row + srow) * 4096 + k0 + schk, sA + row * 64);
        }
        gld16(Bb + (size_t)(w * 8 + srow) * 512 + k0 + schk, sB + w * 8 * 64);
        __syncthreads();
#pragma unroll
        for (int ks = 0; ks < 2; ++ks) {
            bf16x8 af[2], bfr[2];
#pragma unroll
            for (int i = 0; i < 2; ++i)
                af[i] = *(const bf16x8*)&sA[(wm + i * 16 + fr) * 64 + ks * 32 + fq * 8];
#pragma unroll
            for (int j = 0; j < 2; ++j)
                bfr[j] = *(const bf16x8*)&sB[(j * 16 + fr) * 64 + ks * 32 + fq * 8];
#pragma unroll
            for (int i = 0; i < 2; ++i)
#pragma unroll
                for (int j = 0; j < 2; ++j)
                    acc[i][j] = __builtin_amdgcn_mfma_f32_16x16x32_bf16(
                        af[i], bfr[j], acc[i][j], 0, 0, 0);
        }
    }

    float b1v[2], w2v[2][6], br2v[6];
#pragma unroll
    for (int j = 0; j < 2; ++j) {
        int col = j * 16 + fr;
        b1v[j] = br1[s * 32 + col];
#pragma unroll
        for (int e2 = 0; e2 < 6; ++e2) w2v[j][e2] = Wr2[(s * 32 + col) * 6 + e2];
    }
#pragma unroll
    for (int e2 = 0; e2 < 6; ++e2) br2v[e2] = br2[s * 6 + e2];

#pragma unroll
    for (int i = 0; i < 2; ++i) {
#pragma unroll
        for (int r = 0; r < 4; ++r) {
            float lg[6] = {0.f, 0.f, 0.f, 0.f, 0.f, 0.f};
#pragma unroll
            for (int j = 0; j < 2; ++j) {
                float t = fmaxf(acc[i][j][r] + b1v[j], 0.f);
#pragma unroll
                for (int e2 = 0; e2 < 6; ++e2) lg[e2] += t * w2v[j][e2];
            }
#pragma unroll
            for (int e2 = 0; e2 < 6; ++e2) lg[e2] = hsum16(lg[e2]) + br2v[e2];
            float mx = lg[0];
#pragma unroll
            for (int e2 = 1; e2 < 6; ++e2) mx = fmaxf(mx, lg[e2]);
            float p[6], sum = 0.f;
#pragma unroll
            for (int e2 = 0; e2 < 6; ++e2) { p[e2] = __expf(lg[e2] - mx); sum += p[e2]; }
            float inv = __fdividef(1.f, sum);
            if (fr == 0) {
                int brow = b0 + wm + i * 16 + fq * 4 + r;
                float* dst = routing + ((size_t)brow * 8 + s) * 6;
#pragma unroll
                for (int e2 = 0; e2 < 6; ++e2) dst[e2] = p[e2] * inv;
            }
        }
    }
}

// ------- expert layer 1: h1[e][xrow][c] = fp8(tanh(W1t@X^T + b)) -------
// XCD-ownership swizzle: linear%8 XCD slot owns a 6-col-block slab, so each
// XCD's L2 holds only 768 KB of W1t + its h1 slab (fits 4 MB).
// grid = (48 col-blocks, chunk_rows/128 row-blocks); indices remapped inside.
__global__ __launch_bounds__(256, 5) void gemm1_kernel(
    const bf16* __restrict__ A,     // [6144][512] (W1t, all experts)
    const bf16* __restrict__ B,     // xbf chunk [chunk_rows][512]
    const float* __restrict__ bias, // [6144]
    uint8_t* __restrict__ h1,       // [E][chunk_rows][1024] fp8
    int chunk_rows) {
    __shared__ __align__(16) char smem[32768];
    bf16* sA = (bf16*)smem;                    // 128*64 bf16 = 16 KB
    bf16* sB = (bf16*)(smem + 16384);          // 16 KB
    uint8_t* stage = (uint8_t*)smem;           // reused: 128 rows x 144 B = 18 KB
    const int tid = threadIdx.x;
    const int w = tid >> 6, l = tid & 63;
    // --- block swizzle: XCD (lin%8) owns cols [xcd*6, xcd*6+6) ---
    const int lin  = blockIdx.y * gridDim.x + blockIdx.x;
    const int xcd  = lin & 7;
    const int rest = lin >> 3;
    const int m0 = (xcd * 6 + (rest % 6)) * 128;   // h1 col-block (0..6143)
    const int n0 = (rest / 6) * 128;               // xrow-block (chunk-local)
    const int wm = (w & 1) * 64, wn = (w >> 1) * 64;
    const int srow = l >> 3;
    const int gcol = ((l & 7) ^ srow) * 8;   // swizzled source granule
    const int fr = l & 15, fq = l >> 4;
    const int eb = m0 >> 10;           // expert (block-uniform)
    uint8_t* h1e = h1 + (size_t)eb * chunk_rows * H1N;
    const int mloc = m0 & 1023;

    f32x4 acc[4][4];
#pragma unroll
    for (int i = 0; i < 4; ++i)
#pragma unroll
        for (int j = 0; j < 4; ++j) acc[i][j] = (f32x4){0.f, 0.f, 0.f, 0.f};

    for (int k0 = 0; k0 < DBLK; k0 += 64) {
        __syncthreads();
#pragma unroll
        for (int jj = 0; jj < 4; ++jj) {
            int row = w * 32 + jj * 8;
            gld16(A + (size_t)(m0 + row + srow) * DBLK + k0 + gcol, sA + row * 64);
            gld16(B + (size_t)(n0 + row + srow) * DBLK + k0 + gcol, sB + row * 64);
        }
        __syncthreads();
#pragma unroll
        for (int ks = 0; ks < 2; ++ks) {
            bf16x8 af[4], bfr[4];
#pragma unroll
            for (int i = 0; i < 4; ++i)
                af[i] = *(const bf16x8*)&sA[swz(wm + i * 16 + fr, ks * 4 + fq)];
#pragma unroll
            for (int j = 0; j < 4; ++j)
                bfr[j] = *(const bf16x8*)&sB[swz(wn + j * 16 + fr, ks * 4 + fq)];
#pragma unroll
            for (int i = 0; i < 4; ++i)
#pragma unroll
                for (int j = 0; j < 4; ++j)
                    acc[i][j] = __builtin_amdgcn_mfma_f32_16x16x32_bf16(
                        af[i], bfr[j], acc[i][j], 0, 0, 0);
        }
    }

    // ---- epilogue: tanh -> fp8 pack -> LDS stage (144B row pitch) ----
    __syncthreads();   // all LDS reads of the K-loop done before reuse
#pragma unroll
    for (int i = 0; i < 4; ++i) {
        int colb = m0 + wm + i * 16 + fq * 4;          // global col (bias)
        int cloc = wm + i * 16 + fq * 4;               // tile-local col 0..127
        float4 bb = *(const float4*)&bias[colb];
#pragma unroll
        for (int j = 0; j < 4; ++j) {
            int xrow = wn + j * 16 + fr;               // tile-local row 0..127
            float t0 = fast_tanh(acc[i][j][0] + bb.x);
            float t1 = fast_tanh(acc[i][j][1] + bb.y);
            float t2 = fast_tanh(acc[i][j][2] + bb.z);
            float t3 = fast_tanh(acc[i][j][3] + bb.w);
            int p = 0;
            p = __builtin_amdgcn_cvt_pk_fp8_f32(t0, t1, p, false);
            p = __builtin_amdgcn_cvt_pk_fp8_f32(t2, t3, p, true);
            *(uint32_t*)&stage[xrow * 144 + cloc] = (uint32_t)p;  // 2-way max (free)
        }
    }
    __syncthreads();
    // ---- store out: 16B/lane contiguous, 8 rows x 128B (full lines) per instr ----
    const int srow8 = tid >> 3;        // 0..31
    const int schunk = (tid & 7) * 16; // 0..112
#pragma unroll
    for (int pass = 0; pass < 4; ++pass) {
        int rloc = srow8 + pass * 32;
        int4 v = *(const int4*)&stage[rloc * 144 + schunk];
        *(int4*)&h1e[(size_t)(n0 + rloc) * H1N + mloc + schunk] = v;
    }
}

// ------- layer 2+3 (fp8 x fp8): eo[e][xrow] += tanh(h1@W2+b) @ We3 -------
// A = W2f8t rows (h2 cols, x32-scaled), B = h1[e] rows (fp8, cache-resident).
__global__ __launch_bounds__(256, 5) void gemm2_kernel(
    const uint8_t* __restrict__ h1,    // [E][chunk_rows][1024] fp8
    const uint8_t* __restrict__ W2f8t, // [6][512][1024] fp8 (x32)
    const float* __restrict__ be2,     // [6][512]
    const float* __restrict__ We3,     // [6][512][3]
    float* __restrict__ eo,            // [6][32768][3]
    int chunk_rows, int row0) {
    __shared__ __align__(16) uint8_t sA[128 * 64];
    __shared__ __align__(16) uint8_t sB[128 * 64];
    __shared__ float w3s[128 * 3];
    __shared__ float b2s[128];
    const int tid = threadIdx.x;
    const int w = tid >> 6, l = tid & 63;
    const int e  = blockIdx.z;
    const int n0 = blockIdx.x * 128;   // xrows (chunk-local)
    const int m0 = blockIdx.y * 128;   // h2 cols (0..511)
    const int wm = (w & 1) * 64, wn = (w >> 1) * 64;
    const int srow4 = l >> 2;                        // dest row in 16-row group
    const int g4 = (((l & 3) ^ ((l >> 3) & 3)) << 4); // source granule (matches swz8)
    const int fr = l & 15, fq = l >> 4;
    const uint8_t* Ae = W2f8t + (size_t)e * (H2N * H1N);
    const uint8_t* Be = h1 + (size_t)e * chunk_rows * H1N;

    if (tid < 128) {
        int c = m0 + tid;
        b2s[tid] = be2[e * H2N + c];
        w3s[tid * 3 + 0] = We3[((size_t)e * H2N + c) * 3 + 0];
        w3s[tid * 3 + 1] = We3[((size_t)e * H2N + c) * 3 + 1];
        w3s[tid * 3 + 2] = We3[((size_t)e * H2N + c) * 3 + 2];
    }

    f32x4 acc[4][4];
#pragma unroll
    for (int i = 0; i < 4; ++i)
#pragma unroll
        for (int j = 0; j < 4; ++j) acc[i][j] = (f32x4){0.f, 0.f, 0.f, 0.f};

    for (int k0 = 0; k0 < H1N; k0 += 64) {
        __syncthreads();
#pragma unroll
        for (int jj = 0; jj < 2; ++jj) {
            int row = w * 32 + jj * 16 + srow4;
            gld16(Ae + (size_t)(m0 + row) * H1N + k0 + g4, sA + (w * 32 + jj * 16) * 64);
            gld16(Be + (size_t)(n0 + row) * H1N + k0 + g4, sB + (w * 32 + jj * 16) * 64);
        }
        __syncthreads();
#pragma unroll
        for (int ks = 0; ks < 2; ++ks) {
            i64v af[4], bfr[4];
#pragma unroll
            for (int i = 0; i < 4; ++i) {
                int row = wm + i * 16 + fr;
                af[i] = *(const i64v*)&sA[swz8(row, ks * 2 + (fq >> 1)) + ((fq & 1) << 3)];
            }
#pragma unroll
            for (int j = 0; j < 4; ++j) {
                int row = wn + j * 16 + fr;
                bfr[j] = *(const i64v*)&sB[swz8(row, ks * 2 + (fq >> 1)) + ((fq & 1) << 3)];
            }
#pragma unroll
            for (int i = 0; i < 4; ++i)
#pragma unroll
                for (int j = 0; j < 4; ++j)
                    acc[i][j] = __builtin_amdgcn_mfma_f32_16x16x32_fp8_fp8(
                        af[i], bfr[j], acc[i][j], 0, 0, 0);
        }
    }

    // lane holds 16 h2-cols of xrow; layer-3 col-sum in-register; acc is x32-scaled
    float p[4][3];
#pragma unroll
    for (int j = 0; j < 4; ++j) { p[j][0] = 0.f; p[j][1] = 0.f; p[j][2] = 0.f; }
#pragma unroll
    for (int i = 0; i < 4; ++i) {
        int cl = wm + i * 16 + fq * 4;   // local col 0..127
        float4 bb = *(const float4*)&b2s[cl];
        float4 wa = *(const float4*)&w3s[cl * 3 + 0];
        float4 wb = *(const float4*)&w3s[cl * 3 + 4];
        float4 wc = *(const float4*)&w3s[cl * 3 + 8];
        float bias4[4] = {bb.x, bb.y, bb.z, bb.w};
        float w30[4] = {wa.x, wa.w, wb.z, wc.y};
        float w31[4] = {wa.y, wb.x, wb.w, wc.z};
        float w32[4] = {wa.z, wb.y, wc.x, wc.w};
#pragma unroll
        for (int j = 0; j < 4; ++j) {
#pragma unroll
            for (int r = 0; r < 4; ++r) {
                float t = fast_tanh(acc[i][j][r] * W2INV + bias4[r]);
                p[j][0] += t * w30[r];
                p[j][1] += t * w31[r];
                p[j][2] += t * w32[r];
            }
        }
    }
#pragma unroll
    for (int j = 0; j < 4; ++j) {
        float v0 = p[j][0], v1 = p[j][1], v2 = p[j][2];
        v0 += __shfl_xor(v0, 16); v0 += __shfl_xor(v0, 32);
        v1 += __shfl_xor(v1, 16); v1 += __shfl_xor(v1, 32);
        v2 += __shfl_xor(v2, 16); v2 += __shfl_xor(v2, 32);
        if (fq == 0) {
            int xrow = row0 + n0 + wn + j * 16 + fr;
            float* dst = eo + ((size_t)e * NROWS + xrow) * 3;
            atomicAdd(dst + 0, v0);
            atomicAdd(dst + 1, v1);
            atomicAdd(dst + 2, v2);
        }
    }
}

// ---------------- final: routing-weighted mean + aggregator MLP ----------------
__global__ void final_kernel(
    const float* __restrict__ routing, const float* __restrict__ eo,
    const float* __restrict__ be3, const float* __restrict__ Wa1,
    const float* __restrict__ ba1, const float* __restrict__ Wa2,
    const float* __restrict__ ba2, float* __restrict__ out) {
    int b = blockIdx.x * blockDim.x + threadIdx.x;
    if (b >= NBATCH) return;
    float f0 = 0.f, f1 = 0.f, f2 = 0.f;
    for (int s = 0; s < 8; ++s) {
        int r = b * 8 + s;
        const float* rt = routing + (size_t)r * 6;
#pragma unroll
        for (int e = 0; e < 6; ++e) {
            float wgt = rt[e];
            const float* eop = eo + ((size_t)e * NROWS + r) * 3;
            f0 += wgt * (eop[0] + be3[e * 3 + 0]);
            f1 += wgt * (eop[1] + be3[e * 3 + 1]);
            f2 += wgt * (eop[2] + be3[e * 3 + 2]);
        }
    }
    f0 *= 0.125f; f1 *= 0.125f; f2 *= 0.125f;
    float o0 = ba2[0], o1 = ba2[1], o2 = ba2[2];
#pragma unroll
    for (int h = 0; h < 16; ++h) {
        float a = f0 * Wa1[h] + f1 * Wa1[16 + h] + f2 * Wa1[32 + h] + ba1[h];
        a = fmaxf(a, 0.f);
        o0 += a * Wa2[h * 3 + 0];
        o1 += a * Wa2[h * 3 + 1];
        o2 += a * Wa2[h * 3 + 2];
    }
    out[b * 3 + 0] = o0;
    out[b * 3 + 1] = o1;
    out[b * 3 + 2] = o2;
}

// ---------------- host ----------------

extern "C" void kernel_launch(void* const* d_in, const int* in_sizes, int n_in,
                              void* d_out, int out_size, void* d_ws, size_t ws_size,
                              hipStream_t stream) {
    const float* x   = (const float*)d_in[0];
    const float* Wr1 = (const float*)d_in[1];
    const float* br1 = (const float*)d_in[2];
    const float* Wr2 = (const float*)d_in[3];
    const float* br2 = (const float*)d_in[4];
    const float* We1 = (const float*)d_in[5];
    const float* be1 = (const float*)d_in[6];
    const float* We2 = (const float*)d_in[7];
    const float* be2 = (const float*)d_in[8];
    const float* We3 = (const float*)d_in[9];
    const float* be3 = (const float*)d_in[10];
    const float* Wa1 = (const float*)d_in[11];
    const float* ba1 = (const float*)d_in[12];
    const float* Wa2 = (const float*)d_in[13];
    const float* ba2 = (const float*)d_in[14];
    float* out = (float*)d_out;

    char* ws = (char*)d_ws;
    const size_t off_xbf  = 0;                               // 32768*512*2  = 33554432
    const size_t off_w1t  = off_xbf  + (size_t)33554432;     // 6*1024*512*2 = 6291456
    const size_t off_w2t  = off_w1t  + (size_t)6291456;      // 6*512*1024   = 3145728 (fp8, region kept 6291456)
    const size_t off_wr1t = off_w2t  + (size_t)6291456;      // 8*32*512*2   = 262144
    const size_t off_rout = off_wr1t + (size_t)262144;       // 32768*6*4    = 786432
    const size_t off_eo   = off_rout + (size_t)786432;       // 6*32768*3*4  = 2359296
    const size_t off_h1   = off_eo   + (size_t)2359296;      // base = 49545216

    // fixed split=8: h1 chunk = [E][4096][1024] fp8 = 25 MB -> L2/L3 resident
    if (off_h1 + ((size_t)NROWS / SPLIT) * HALL > ws_size) return;  // diagnostic

    bf16*    xbf     = (bf16*)(ws + off_xbf);
    bf16*    W1t     = (bf16*)(ws + off_w1t);
    uint8_t* W2f8t   = (uint8_t*)(ws + off_w2t);
    bf16*    Wr1t    = (bf16*)(ws + off_wr1t);
    float*   routing = (float*)(ws + off_rout);
    float*   eo      = (float*)(ws + off_eo);
    uint8_t* h1      = (uint8_t*)(ws + off_h1);

    // prep
    cvt_bf16_kernel<<<16384, 256, 0, stream>>>(x, xbf, 4194304);
    transpose_cvt<<<dim3(16, 8, 6), 256, 0, stream>>>(We1, W1t, 512, 1024);
    transpose_cvt_fp8<<<dim3(8, 16, 6), 256, 0, stream>>>(We2, W2f8t, 1024, 512, W2SCALE);
    transpose_cvt<<<dim3(1, 8, 8), 256, 0, stream>>>(Wr1, Wr1t, 512, 32);
    zero_f32_kernel<<<2304, 256, 0, stream>>>(eo, 589824);

    // router
    router_kernel<<<dim3(32, 8), 256, 0, stream>>>(xbf, Wr1t, br1, Wr2, br2, routing);

    // experts: interleaved per row-chunk so h1 stays cache-resident
    const int chunk_rows = NROWS / SPLIT;   // 4096
    for (int c = 0; c < SPLIT; ++c) {
        const int row0 = c * chunk_rows;
        gemm1_kernel<<<dim3(HALL / 128, chunk_rows / 128), 256, 0, stream>>>(
            W1t, xbf + (size_t)row0 * DBLK, be1, h1, chunk_rows);
        gemm2_kernel<<<dim3(chunk_rows / 128, H2N / 128, NEXP), 256, 0, stream>>>(
            h1, W2f8t, be2, We3, eo, chunk_rows, row0);
    }

    // aggregate
    final_kernel<<<16, 256, 0, stream>>>(routing, eo, be3, Wa1, ba1, Wa2, ba2, out);
}

// Round 8
// 626.934 us; speedup vs baseline: 1.7851x; 1.7851x over previous
//
#include <hip/hip_runtime.h>
#include <cstdint>
#include <cstddef>

typedef __bf16 bf16;
typedef __bf16 bf16x4 __attribute__((ext_vector_type(4)));
typedef __bf16 bf16x8 __attribute__((ext_vector_type(8)));
typedef float  f32x4  __attribute__((ext_vector_type(4)));
typedef long long i64v;

#define NROWS   32768   // 4096 * 8  (X2 rows)
#define DBLK    512
#define H1N     1024
#define H2N     512
#define NEXP    6
#define NBATCH  4096
#define HALL    (NEXP * H1N)   // 6144 h1 cols across all experts
#define W2SCALE 32.0f
#define W2INV   0.03125f

// async global->LDS, 16B per lane; LDS dest = wave-uniform base + lane*16
__device__ __forceinline__ void gld16(const void* g, void* l) {
    __builtin_amdgcn_global_load_lds(
        (const __attribute__((address_space(1))) void*)g,
        (__attribute__((address_space(3))) void*)l, 16, 0, 0);
}

// inf-safe fast tanh: 1 - 2/(exp(2x)+1)
__device__ __forceinline__ float fast_tanh(float x) {
    float e = __expf(2.0f * x);
    return 1.0f - __fdividef(2.0f, e + 1.0f);
}

__device__ __forceinline__ float hsum16(float v) {
    v += __shfl_xor(v, 1);
    v += __shfl_xor(v, 2);
    v += __shfl_xor(v, 4);
    v += __shfl_xor(v, 8);
    return v;
}

// bf16 tiles: swizzled LDS element offset (16B granule g of row r at g^(r&7))
__device__ __forceinline__ int swz(int row, int g) {
    return row * 64 + ((g ^ (row & 7)) * 8);
}
// fp8 tiles: 64B rows, 4 granules; granule g of row r lives at g^((r>>1)&3)
__device__ __forceinline__ int swz8(int row, int g) {
    return row * 64 + ((g ^ ((row >> 1) & 3)) << 4);
}

// ---------------- prep kernels ----------------

__global__ void cvt_bf16_kernel(const float* __restrict__ in,
                                bf16* __restrict__ out, int n4) {
    int i = blockIdx.x * blockDim.x + threadIdx.x;
    if (i >= n4) return;
    float4 v = ((const float4*)in)[i];
    bf16x4 o;
    o.x = (bf16)v.x; o.y = (bf16)v.y; o.z = (bf16)v.z; o.w = (bf16)v.w;
    ((bf16x4*)out)[i] = o;
}

// in: [E][K][N] f32 -> out: [E][N][K] bf16 (LDS-tiled transpose)
__global__ __launch_bounds__(256) void transpose_cvt(
    const float* __restrict__ in, bf16* __restrict__ out, int K, int N) {
    __shared__ bf16 tile[64][66];
    int e  = blockIdx.z;
    int n0 = blockIdx.x * 64;
    int k0 = blockIdx.y * 64;
    int c  = threadIdx.x & 63;
    int rb = threadIdx.x >> 6;   // 0..3
    const float* src = in + (size_t)e * K * N;
    bf16* dst = out + (size_t)e * N * K;
#pragma unroll
    for (int it = 0; it < 16; ++it) {
        int k = k0 + rb + it * 4;
        int n = n0 + c;
        if (k < K && n < N) tile[rb + it * 4][c] = (bf16)src[(size_t)k * N + n];
    }
    __syncthreads();
#pragma unroll
    for (int it = 0; it < 16; ++it) {
        int n = n0 + rb + it * 4;
        int k = k0 + c;
        if (n < N && k < K) dst[(size_t)n * K + k] = tile[c][rb + it * 4];
    }
}

// in: [E][K][N] f32 -> out: [E][N][K] fp8 e4m3, scaled
__global__ __launch_bounds__(256) void transpose_cvt_fp8(
    const float* __restrict__ in, uint8_t* __restrict__ out, int K, int N,
    float scale) {
    __shared__ float tile[64][65];
    int e  = blockIdx.z;
    int n0 = blockIdx.x * 64;
    int k0 = blockIdx.y * 64;
    int c  = threadIdx.x & 63;
    int rb = threadIdx.x >> 6;   // 0..3
    const float* src = in + (size_t)e * K * N;
    uint8_t* dst = out + (size_t)e * N * K;
#pragma unroll
    for (int it = 0; it < 16; ++it) {
        int k = k0 + rb + it * 4;
        int n = n0 + c;
        if (k < K && n < N) tile[rb + it * 4][c] = src[(size_t)k * N + n];
    }
    __syncthreads();
#pragma unroll
    for (int it = 0; it < 16; ++it) {
        int n = n0 + rb + it * 4;
        int k = k0 + c;
        if (n < N && k < K) {
            float v = tile[c][rb + it * 4] * scale;
            int p = __builtin_amdgcn_cvt_pk_fp8_f32(v, v, 0, false);
            dst[(size_t)n * K + k] = (uint8_t)(p & 0xff);
        }
    }
}

__global__ void zero_f32_kernel(float* __restrict__ p, int n) {
    int i = blockIdx.x * blockDim.x + threadIdx.x;
    if (i < n) p[i] = 0.0f;
}

// ---------------- router ----------------

__global__ __launch_bounds__(256, 2) void router_kernel(
    const bf16* __restrict__ xbf,   // [4096][4096]
    const bf16* __restrict__ Wr1t,  // [8][32][512]
    const float* __restrict__ br1,  // [8][32]
    const float* __restrict__ Wr2,  // [8][32][6]
    const float* __restrict__ br2,  // [8][6]
    float* __restrict__ routing) {  // [32768][6]
    __shared__ __align__(16) bf16 sA[128 * 64];
    __shared__ __align__(16) bf16 sB[32 * 64];
    const int tid = threadIdx.x;
    const int w = tid >> 6, l = tid & 63;
    const int s  = blockIdx.y;
    const int b0 = blockIdx.x * 128;
    const int wm = w * 32;
    const int srow = l >> 3, schk = (l & 7) * 8;
    const int fr = l & 15, fq = l >> 4;
    const bf16* Ab = xbf + (size_t)s * 512;
    const bf16* Bb = Wr1t + (size_t)s * (32 * 512);

    f32x4 acc[2][2];
#pragma unroll
    for (int i = 0; i < 2; ++i)
#pragma unroll
        for (int j = 0; j < 2; ++j) acc[i][j] = (f32x4){0.f, 0.f, 0.f, 0.f};

    for (int k0 = 0; k0 < 512; k0 += 64) {
        __syncthreads();
#pragma unroll
        for (int jj = 0; jj < 4; ++jj) {
            int row = w * 32 + jj * 8;
            gld16(Ab + (size_t)(b0 + row + srow) * 4096 + k0 + schk, sA + row * 64);
        }
        gld16(Bb + (size_t)(w * 8 + srow) * 512 + k0 + schk, sB + w * 8 * 64);
        __syncthreads();
#pragma unroll
        for (int ks = 0; ks < 2; ++ks) {
            bf16x8 af[2], bfr[2];
#pragma unroll
            for (int i = 0; i < 2; ++i)
                af[i] = *(const bf16x8*)&sA[(wm + i * 16 + fr) * 64 + ks * 32 + fq * 8];
#pragma unroll
            for (int j = 0; j < 2; ++j)
                bfr[j] = *(const bf16x8*)&sB[(j * 16 + fr) * 64 + ks * 32 + fq * 8];
#pragma unroll
            for (int i = 0; i < 2; ++i)
#pragma unroll
                for (int j = 0; j < 2; ++j)
                    acc[i][j] = __builtin_amdgcn_mfma_f32_16x16x32_bf16(
                        af[i], bfr[j], acc[i][j], 0, 0, 0);
        }
    }

    float b1v[2], w2v[2][6], br2v[6];
#pragma unroll
    for (int j = 0; j < 2; ++j) {
        int col = j * 16 + fr;
        b1v[j] = br1[s * 32 + col];
#pragma unroll
        for (int e2 = 0; e2 < 6; ++e2) w2v[j][e2] = Wr2[(s * 32 + col) * 6 + e2];
    }
#pragma unroll
    for (int e2 = 0; e2 < 6; ++e2) br2v[e2] = br2[s * 6 + e2];

#pragma unroll
    for (int i = 0; i < 2; ++i) {
#pragma unroll
        for (int r = 0; r < 4; ++r) {
            float lg[6] = {0.f, 0.f, 0.f, 0.f, 0.f, 0.f};
#pragma unroll
            for (int j = 0; j < 2; ++j) {
                float t = fmaxf(acc[i][j][r] + b1v[j], 0.f);
#pragma unroll
                for (int e2 = 0; e2 < 6; ++e2) lg[e2] += t * w2v[j][e2];
            }
#pragma unroll
            for (int e2 = 0; e2 < 6; ++e2) lg[e2] = hsum16(lg[e2]) + br2v[e2];
            float mx = lg[0];
#pragma unroll
            for (int e2 = 1; e2 < 6; ++e2) mx = fmaxf(mx, lg[e2]);
            float p[6], sum = 0.f;
#pragma unroll
            for (int e2 = 0; e2 < 6; ++e2) { p[e2] = __expf(lg[e2] - mx); sum += p[e2]; }
            float inv = __fdividef(1.f, sum);
            if (fr == 0) {
                int brow = b0 + wm + i * 16 + fq * 4 + r;
                float* dst = routing + ((size_t)brow * 8 + s) * 6;
#pragma unroll
                for (int e2 = 0; e2 < 6; ++e2) dst[e2] = p[e2] * inv;
            }
        }
    }
}

// ------- expert layer 1 (R3 grid/structure): h1[xrow][col] = fp8(tanh(W1t@X^T+b)) -------
// A = W1t rows (h1 cols over ALL experts, k-contig), B = X rows (k-contig).
// grid (x=row-blocks, y=col-blocks) — x-fastest ordering measured 4x lower TCC traffic.
__global__ __launch_bounds__(256, 4) void gemm1_kernel(
    const bf16* __restrict__ A,     // [6144][512] (W1t, all experts)
    const bf16* __restrict__ B,     // xbf [32768][512]
    const float* __restrict__ bias, // [6144]
    uint8_t* __restrict__ h1,       // [32768][6144] fp8, col-interleaved
    int ldh) {
    __shared__ __align__(16) bf16 sA[128 * 64];
    __shared__ __align__(16) bf16 sB[128 * 64];
    const int tid = threadIdx.x;
    const int w = tid >> 6, l = tid & 63;
    const int n0 = blockIdx.x * 128;   // xrows
    const int m0 = blockIdx.y * 128;   // h1 cols (0..6143)
    const int wm = (w & 1) * 64, wn = (w >> 1) * 64;
    const int srow = l >> 3;
    const int gcol = ((l & 7) ^ srow) * 8;   // swizzled source granule
    const int fr = l & 15, fq = l >> 4;

    f32x4 acc[4][4];
#pragma unroll
    for (int i = 0; i < 4; ++i)
#pragma unroll
        for (int j = 0; j < 4; ++j) acc[i][j] = (f32x4){0.f, 0.f, 0.f, 0.f};

    for (int k0 = 0; k0 < DBLK; k0 += 64) {
        __syncthreads();
#pragma unroll
        for (int jj = 0; jj < 4; ++jj) {
            int row = w * 32 + jj * 8;
            gld16(A + (size_t)(m0 + row + srow) * DBLK + k0 + gcol, sA + row * 64);
            gld16(B + (size_t)(n0 + row + srow) * DBLK + k0 + gcol, sB + row * 64);
        }
        __syncthreads();
#pragma unroll
        for (int ks = 0; ks < 2; ++ks) {
            bf16x8 af[4], bfr[4];
#pragma unroll
            for (int i = 0; i < 4; ++i)
                af[i] = *(const bf16x8*)&sA[swz(wm + i * 16 + fr, ks * 4 + fq)];
#pragma unroll
            for (int j = 0; j < 4; ++j)
                bfr[j] = *(const bf16x8*)&sB[swz(wn + j * 16 + fr, ks * 4 + fq)];
#pragma unroll
            for (int i = 0; i < 4; ++i)
#pragma unroll
                for (int j = 0; j < 4; ++j)
                    acc[i][j] = __builtin_amdgcn_mfma_f32_16x16x32_bf16(
                        af[i], bfr[j], acc[i][j], 0, 0, 0);
        }
    }

    // lane holds 4 consecutive h1-cols (m=fq*4+r) for xrow n=fr -> pack fp8 -> 4B store
#pragma unroll
    for (int i = 0; i < 4; ++i) {
        int colb = m0 + wm + i * 16 + fq * 4;
        float4 bb = *(const float4*)&bias[colb];
#pragma unroll
        for (int j = 0; j < 4; ++j) {
            int xrow = n0 + wn + j * 16 + fr;
            float t0 = fast_tanh(acc[i][j][0] + bb.x);
            float t1 = fast_tanh(acc[i][j][1] + bb.y);
            float t2 = fast_tanh(acc[i][j][2] + bb.z);
            float t3 = fast_tanh(acc[i][j][3] + bb.w);
            int p = 0;
            p = __builtin_amdgcn_cvt_pk_fp8_f32(t0, t1, p, false);
            p = __builtin_amdgcn_cvt_pk_fp8_f32(t2, t3, p, true);
            *(uint32_t*)&h1[(size_t)xrow * ldh + colb] = (uint32_t)p;
        }
    }
}

// ------- layer 2+3 (fp8 x fp8, R7-fixed swizzle, R3 grid): eo += tanh(h1@W2+b)@We3 -------
// A = W2f8t rows (h2 cols, x32-scaled), B = h1 rows (fp8, col band e*1024).
__global__ __launch_bounds__(256, 4) void gemm2_kernel(
    const uint8_t* __restrict__ h1,    // [32768][6144] fp8
    const uint8_t* __restrict__ W2f8t, // [6][512][1024] fp8 (x32)
    const float* __restrict__ be2,     // [6][512]
    const float* __restrict__ We3,     // [6][512][3]
    float* __restrict__ eo,            // [6][32768][3]
    int ldh) {
    __shared__ __align__(16) uint8_t sA[128 * 64];
    __shared__ __align__(16) uint8_t sB[128 * 64];
    __shared__ float w3s[128 * 3];
    __shared__ float b2s[128];
    const int tid = threadIdx.x;
    const int w = tid >> 6, l = tid & 63;
    const int e  = blockIdx.z;
    const int n0 = blockIdx.x * 128;   // xrows
    const int m0 = blockIdx.y * 128;   // h2 cols (0..511)
    const int wm = (w & 1) * 64, wn = (w >> 1) * 64;
    const int srow4 = l >> 2;                         // dest row within 16-row group
    const int g4 = (((l & 3) ^ ((l >> 3) & 3)) << 4); // source granule (matches swz8)
    const int fr = l & 15, fq = l >> 4;
    const uint8_t* Ae = W2f8t + (size_t)e * (H2N * H1N);
    const uint8_t* Be = h1 + (size_t)e * H1N;   // column band within ldh=6144

    if (tid < 128) {
        int c = m0 + tid;
        b2s[tid] = be2[e * H2N + c];
        w3s[tid * 3 + 0] = We3[((size_t)e * H2N + c) * 3 + 0];
        w3s[tid * 3 + 1] = We3[((size_t)e * H2N + c) * 3 + 1];
        w3s[tid * 3 + 2] = We3[((size_t)e * H2N + c) * 3 + 2];
    }

    f32x4 acc[4][4];
#pragma unroll
    for (int i = 0; i < 4; ++i)
#pragma unroll
        for (int j = 0; j < 4; ++j) acc[i][j] = (f32x4){0.f, 0.f, 0.f, 0.f};

    for (int k0 = 0; k0 < H1N; k0 += 64) {
        __syncthreads();
#pragma unroll
        for (int jj = 0; jj < 2; ++jj) {
            int row = w * 32 + jj * 16 + srow4;
            gld16(Ae + (size_t)(m0 + row) * H1N + k0 + g4, sA + (w * 32 + jj * 16) * 64);
            gld16(Be + (size_t)(n0 + row) * ldh + k0 + g4, sB + (w * 32 + jj * 16) * 64);
        }
        __syncthreads();
#pragma unroll
        for (int ks = 0; ks < 2; ++ks) {
            i64v af[4], bfr[4];
#pragma unroll
            for (int i = 0; i < 4; ++i) {
                int row = wm + i * 16 + fr;
                af[i] = *(const i64v*)&sA[swz8(row, ks * 2 + (fq >> 1)) + ((fq & 1) << 3)];
            }
#pragma unroll
            for (int j = 0; j < 4; ++j) {
                int row = wn + j * 16 + fr;
                bfr[j] = *(const i64v*)&sB[swz8(row, ks * 2 + (fq >> 1)) + ((fq & 1) << 3)];
            }
#pragma unroll
            for (int i = 0; i < 4; ++i)
#pragma unroll
                for (int j = 0; j < 4; ++j)
                    acc[i][j] = __builtin_amdgcn_mfma_f32_16x16x32_fp8_fp8(
                        af[i], bfr[j], acc[i][j], 0, 0, 0);
        }
    }

    // lane holds 16 h2-cols of xrow; layer-3 col-sum in-register; acc is x32-scaled
    float p[4][3];
#pragma unroll
    for (int j = 0; j < 4; ++j) { p[j][0] = 0.f; p[j][1] = 0.f; p[j][2] = 0.f; }
#pragma unroll
    for (int i = 0; i < 4; ++i) {
        int cl = wm + i * 16 + fq * 4;   // local col 0..127
        float4 bb = *(const float4*)&b2s[cl];
        float4 wa = *(const float4*)&w3s[cl * 3 + 0];
        float4 wb = *(const float4*)&w3s[cl * 3 + 4];
        float4 wc = *(const float4*)&w3s[cl * 3 + 8];
        float bias4[4] = {bb.x, bb.y, bb.z, bb.w};
        float w30[4] = {wa.x, wa.w, wb.z, wc.y};
        float w31[4] = {wa.y, wb.x, wb.w, wc.z};
        float w32[4] = {wa.z, wb.y, wc.x, wc.w};
#pragma unroll
        for (int j = 0; j < 4; ++j) {
#pragma unroll
            for (int r = 0; r < 4; ++r) {
                float t = fast_tanh(acc[i][j][r] * W2INV + bias4[r]);
                p[j][0] += t * w30[r];
                p[j][1] += t * w31[r];
                p[j][2] += t * w32[r];
            }
        }
    }
#pragma unroll
    for (int j = 0; j < 4; ++j) {
        float v0 = p[j][0], v1 = p[j][1], v2 = p[j][2];
        v0 += __shfl_xor(v0, 16); v0 += __shfl_xor(v0, 32);
        v1 += __shfl_xor(v1, 16); v1 += __shfl_xor(v1, 32);
        v2 += __shfl_xor(v2, 16); v2 += __shfl_xor(v2, 32);
        if (fq == 0) {
            int xrow = n0 + wn + j * 16 + fr;
            float* dst = eo + ((size_t)e * NROWS + xrow) * 3;
            atomicAdd(dst + 0, v0);
            atomicAdd(dst + 1, v1);
            atomicAdd(dst + 2, v2);
        }
    }
}

// ---------------- final: routing-weighted mean + aggregator MLP ----------------
__global__ void final_kernel(
    const float* __restrict__ routing, const float* __restrict__ eo,
    const float* __restrict__ be3, const float* __restrict__ Wa1,
    const float* __restrict__ ba1, const float* __restrict__ Wa2,
    const float* __restrict__ ba2, float* __restrict__ out) {
    int b = blockIdx.x * blockDim.x + threadIdx.x;
    if (b >= NBATCH) return;
    float f0 = 0.f, f1 = 0.f, f2 = 0.f;
    for (int s = 0; s < 8; ++s) {
        int r = b * 8 + s;
        const float* rt = routing + (size_t)r * 6;
#pragma unroll
        for (int e = 0; e < 6; ++e) {
            float wgt = rt[e];
            const float* eop = eo + ((size_t)e * NROWS + r) * 3;
            f0 += wgt * (eop[0] + be3[e * 3 + 0]);
            f1 += wgt * (eop[1] + be3[e * 3 + 1]);
            f2 += wgt * (eop[2] + be3[e * 3 + 2]);
        }
    }
    f0 *= 0.125f; f1 *= 0.125f; f2 *= 0.125f;
    float o0 = ba2[0], o1 = ba2[1], o2 = ba2[2];
#pragma unroll
    for (int h = 0; h < 16; ++h) {
        float a = f0 * Wa1[h] + f1 * Wa1[16 + h] + f2 * Wa1[32 + h] + ba1[h];
        a = fmaxf(a, 0.f);
        o0 += a * Wa2[h * 3 + 0];
        o1 += a * Wa2[h * 3 + 1];
        o2 += a * Wa2[h * 3 + 2];
    }
    out[b * 3 + 0] = o0;
    out[b * 3 + 1] = o1;
    out[b * 3 + 2] = o2;
}

// ---------------- host ----------------

extern "C" void kernel_launch(void* const* d_in, const int* in_sizes, int n_in,
                              void* d_out, int out_size, void* d_ws, size_t ws_size,
                              hipStream_t stream) {
    const float* x   = (const float*)d_in[0];
    const float* Wr1 = (const float*)d_in[1];
    const float* br1 = (const float*)d_in[2];
    const float* Wr2 = (const float*)d_in[3];
    const float* br2 = (const float*)d_in[4];
    const float* We1 = (const float*)d_in[5];
    const float* be1 = (const float*)d_in[6];
    const float* We2 = (const float*)d_in[7];
    const float* be2 = (const float*)d_in[8];
    const float* We3 = (const float*)d_in[9];
    const float* be3 = (const float*)d_in[10];
    const float* Wa1 = (const float*)d_in[11];
    const float* ba1 = (const float*)d_in[12];
    const float* Wa2 = (const float*)d_in[13];
    const float* ba2 = (const float*)d_in[14];
    float* out = (float*)d_out;

    char* ws = (char*)d_ws;
    const size_t off_xbf  = 0;                               // 32768*512*2  = 33554432
    const size_t off_w1t  = off_xbf  + (size_t)33554432;     // 6*1024*512*2 = 6291456
    const size_t off_w2t  = off_w1t  + (size_t)6291456;      // 6*512*1024 fp8 (region 6291456)
    const size_t off_wr1t = off_w2t  + (size_t)6291456;      // 8*32*512*2   = 262144
    const size_t off_rout = off_wr1t + (size_t)262144;       // 32768*6*4    = 786432
    const size_t off_eo   = off_rout + (size_t)786432;       // 6*32768*3*4  = 2359296
    const size_t off_h1   = off_eo   + (size_t)2359296;      // base = 49545216

    // h1 fp8 [32768][6144] = 201.3 MB; total 250.9 MB (same bound R3 passed)
    if (off_h1 + (size_t)NROWS * HALL > ws_size) return;  // diagnostic

    bf16*    xbf     = (bf16*)(ws + off_xbf);
    bf16*    W1t     = (bf16*)(ws + off_w1t);
    uint8_t* W2f8t   = (uint8_t*)(ws + off_w2t);
    bf16*    Wr1t    = (bf16*)(ws + off_wr1t);
    float*   routing = (float*)(ws + off_rout);
    float*   eo      = (float*)(ws + off_eo);
    uint8_t* h1      = (uint8_t*)(ws + off_h1);

    // prep
    cvt_bf16_kernel<<<16384, 256, 0, stream>>>(x, xbf, 4194304);
    transpose_cvt<<<dim3(16, 8, 6), 256, 0, stream>>>(We1, W1t, 512, 1024);
    transpose_cvt_fp8<<<dim3(8, 16, 6), 256, 0, stream>>>(We2, W2f8t, 1024, 512, W2SCALE);
    transpose_cvt<<<dim3(1, 8, 8), 256, 0, stream>>>(Wr1, Wr1t, 512, 32);
    zero_f32_kernel<<<2304, 256, 0, stream>>>(eo, 589824);

    // router
    router_kernel<<<dim3(32, 8), 256, 0, stream>>>(xbf, Wr1t, br1, Wr2, br2, routing);

    // experts: single g1 + single g2 dispatch (split=1, fp8 h1)
    gemm1_kernel<<<dim3(NROWS / 128, HALL / 128), 256, 0, stream>>>(
        W1t, xbf, be1, h1, HALL);
    gemm2_kernel<<<dim3(NROWS / 128, H2N / 128, NEXP), 256, 0, stream>>>(
        h1, W2f8t, be2, We3, eo, HALL);

    // aggregate
    final_kernel<<<16, 256, 0, stream>>>(routing, eo, be3, Wa1, ba1, Wa2, ba2, out);
}